// Round 5
// baseline (672.210 us; speedup 1.0000x reference)
//
#include <hip/hip_runtime.h>
#include <math.h>

namespace {

constexpr int kB = 64;
constexpr int kN = 4096;
constexpr int kM = 128;
constexpr int kH = 512;
constexpr int kE = 256;
constexpr int kO = 256;
constexpr int kGates = 4 * kH;      // 2048
constexpr int kCatW = 3 * kM + kH;  // 896
constexpr int kPRow = 1600;         // padded 1572
constexpr int kWN = kB * kN;
constexpr int GRID = 512;           // 2 blocks/CU -> 16 waves/CU latency hiding
constexpr int TPB = 512;
constexpr float kLog2e = 1.4426950408889634f;

__device__ __forceinline__ float sigm_(float x) { return 1.f / (1.f + expf(-x)); }
__device__ __forceinline__ float softplus_(float x) { return x > 20.f ? x : log1pf(expf(x)); }

struct Args {
  const float *x, *h_prev, *c_prev, *bank, *read_w_prev, *write_w_prev;
  const float *W_ih, *W_hh, *b_ih, *b_hh, *read_W, *read_b, *write_W, *write_b, *out_W, *out_b;
  float *out;
  float *gates0, *gates1, *gates2, *gates3, *praw0, *praw1, *cat;
  float *kwb, *krb, *evb, *avb, *scal, *sdot;
  float *wp0, *wp1, *wp2, *wp3, *wp4, *wp5;
  float *mA, *mB;
  unsigned *gcnt;   // global barrier counter
  unsigned *bcnt;   // per-batch counters, stride 32 u32 (128 B) each
};

union SMem {
  struct { float At[64 * 20]; float Wt[64 * 65]; } g;   // gates tiles
  struct { float hs[256 * 10]; float Wt[64 * 65]; } p;  // proj: 8-batch h-slice + W tile
  struct { float wb[kN]; float red[8]; } a;             // addressing
  struct { float nred[4][2]; } s;                       // split norms
  struct { float rl[2 * kM]; } r;                       // passB/C read reduce
};

// Barrier primitive. CRITICAL: poll with RELAXED loads (no per-iteration cache
// invalidation); one release fence (writeback) before arrival, one acquire
// fence (inv) after exit. (Round-1 evidence: acquire-polling = L2 inv storm.)
__device__ __forceinline__ void barrier_on(unsigned* c, unsigned target) {
  __syncthreads();
  if (threadIdx.x == 0) {
    __builtin_amdgcn_fence(__ATOMIC_RELEASE, "agent");
    __hip_atomic_fetch_add(c, 1u, __ATOMIC_RELAXED, __HIP_MEMORY_SCOPE_AGENT);
    while (__hip_atomic_load(c, __ATOMIC_RELAXED, __HIP_MEMORY_SCOPE_AGENT) < target)
      __builtin_amdgcn_s_sleep(1);
    __builtin_amdgcn_fence(__ATOMIC_ACQUIRE, "agent");
  }
  __syncthreads();
}

// 512-thread addressing core, 8 elems/thread (N=4096)
__device__ void addr_core8(int tid, float* loc, const float* sc, const float* __restrict__ wp,
                           float* wb, float* red) {
  const float g = sc[1], r = sc[2];
  const float s0 = sc[3], s1c = sc[4], s2 = sc[5];
  const int lane = tid & 63, wid = tid >> 6;  // wid 0..7
  __syncthreads();
  float mx = loc[0];
#pragma unroll
  for (int i = 1; i < 8; i++) mx = fmaxf(mx, loc[i]);
#pragma unroll
  for (int m = 1; m < 64; m <<= 1) mx = fmaxf(mx, __shfl_xor(mx, m, 64));
  if (lane == 0) red[wid] = mx;
  __syncthreads();
  mx = red[0];
#pragma unroll
  for (int k = 1; k < 8; k++) mx = fmaxf(mx, red[k]);
  float sum = 0.f;
#pragma unroll
  for (int i = 0; i < 8; i++) { loc[i] = exp2f((loc[i] - mx) * kLog2e); sum += loc[i]; }
#pragma unroll
  for (int m = 1; m < 64; m <<= 1) sum += __shfl_xor(sum, m, 64);
  __syncthreads();
  if (lane == 0) red[wid] = sum;
  __syncthreads();
  sum = red[0];
#pragma unroll
  for (int k = 1; k < 8; k++) sum += red[k];
  const float inv = 1.f / sum;
  const float omg = 1.f - g;
#pragma unroll
  for (int i = 0; i < 8; i++) {
    int n = tid + i * TPB;
    wb[n] = loc[i] * inv + omg * wp[n];
  }
  __syncthreads();
  float ssum = 0.f;
#pragma unroll
  for (int i = 0; i < 8; i++) {
    int n = tid + i * TPB;
    float sh = s0 * wb[(n + kN - 1) & (kN - 1)] + s1c * wb[n] + s2 * wb[(n + 1) & (kN - 1)];
    float y = (sh > 0.f) ? exp2f(r * log2f(sh)) : 0.f;
    loc[i] = y;
    ssum += y;
  }
#pragma unroll
  for (int m = 1; m < 64; m <<= 1) ssum += __shfl_xor(ssum, m, 64);
  __syncthreads();
  if (lane == 0) red[wid] = ssum;
  __syncthreads();
  ssum = red[0];
#pragma unroll
  for (int k = 1; k < 8; k++) ssum += red[k];
  const float invs = 1.f / (ssum + 1e-8f);
#pragma unroll
  for (int i = 0; i < 8; i++) loc[i] *= invs;
  __syncthreads();
}

__global__ __launch_bounds__(TPB, 4) void mega(Args P) {
  const int bid = blockIdx.x;
  const int tid = threadIdx.x;
  __shared__ SMem sm;

  // Per-batch group: batch = bid & 63, member sub = bid >> 6 (0..7).
  // Group {b, b+64, ..., b+448} shares bid%8 -> same XCD under round-robin.
  const int bb_ = bid & 63;
  const int sub_ = bid >> 6;
  unsigned* bc = P.bcnt + bb_ * 32;

  // =============== Phase G: gates GEMM, 4-way k-split (512 blocks) ===============
  {
    const int quarter = bid >> 7;       // 0..3
    const int unit = bid & 127;
    const int b0 = (unit >> 5) * 16;
    const int j0 = (unit & 31) * 64;
    const int jg = tid & 63;
    const int bq2 = (tid >> 6) * 2;
    float acc0 = 0.f, acc1 = 0.f;
    for (int kc3 = 0; kc3 < 3; kc3++) {
      const int kc = quarter * 3 + kc3;
      const bool isx = kc < 4;
      const float* A = isx ? P.x : P.h_prev;
      const float* W = isx ? P.W_ih : P.W_hh;
      const int lda = isx ? kE : kH;
      const int k0 = (isx ? kc : (kc - 4)) * 64;
      __syncthreads();
      {  // A tile: 16 b x 64 k
        int bb = tid >> 5;
        int kk = (tid & 31) * 2;
        float2 v = *(const float2*)(A + (size_t)(b0 + bb) * lda + k0 + kk);
        sm.g.At[(kk + 0) * 20 + bb] = v.x;
        sm.g.At[(kk + 1) * 20 + bb] = v.y;
      }
#pragma unroll
      for (int i = 0; i < 2; i++) {  // W tile: 64 j x 64 k
        int idx = tid + i * 512;
        int jj = idx >> 4;
        int kk = (idx & 15) * 4;
        float4 w = *(const float4*)(W + (size_t)(j0 + jj) * lda + k0 + kk);
        sm.g.Wt[(kk + 0) * 65 + jj] = w.x; sm.g.Wt[(kk + 1) * 65 + jj] = w.y;
        sm.g.Wt[(kk + 2) * 65 + jj] = w.z; sm.g.Wt[(kk + 3) * 65 + jj] = w.w;
      }
      __syncthreads();
#pragma unroll 4
      for (int k = 0; k < 64; k++) {
        float2 av = *(const float2*)&sm.g.At[k * 20 + bq2];
        float wv = sm.g.Wt[k * 65 + jg];
        acc0 += av.x * wv; acc1 += av.y * wv;
      }
    }
    float* gd = quarter == 0 ? P.gates0 : quarter == 1 ? P.gates1
              : quarter == 2 ? P.gates2 : P.gates3;
    gd[(size_t)(b0 + bq2 + 0) * kGates + j0 + jg] = acc0;
    gd[(size_t)(b0 + bq2 + 1) * kGates + j0 + jg] = acc1;
  }
  barrier_on(P.gcnt, GRID * 1);

  // ====== Phase P: proj GEMM w/ fused h recompute, 2-way k-split (400 blocks) ======
  // 8 bslices x 25 j-tiles x 2 k-halves = 400 units
  if (bid < 400) {
    const int kh = bid / 200;
    const int u = bid % 200;
    const int b0 = (u / 25) * 8;
    const int jt = u % 25;
    const int j0 = jt * 64;
    const int kbase = kh * 256;
    // recompute h for 8 batches, k in [kbase, kbase+256): 2048 vals, 4/thread
    for (int i = tid; i < 8 * 256; i += TPB) {
      int bb = i >> 8, kl = i & 255;
      int kk = kbase + kl;
      int b = b0 + bb;
      const float* g0 = P.gates0 + (size_t)b * kGates;
      const float* g1 = P.gates1 + (size_t)b * kGates;
      const float* g2 = P.gates2 + (size_t)b * kGates;
      const float* g3 = P.gates3 + (size_t)b * kGates;
      float i_ = g0[kk]        + g1[kk]        + g2[kk]        + g3[kk]        + P.b_ih[kk]        + P.b_hh[kk];
      float f_ = g0[512 + kk]  + g1[512 + kk]  + g2[512 + kk]  + g3[512 + kk]  + P.b_ih[512 + kk]  + P.b_hh[512 + kk];
      float gg = g0[1024 + kk] + g1[1024 + kk] + g2[1024 + kk] + g3[1024 + kk] + P.b_ih[1024 + kk] + P.b_hh[1024 + kk];
      float o_ = g0[1536 + kk] + g1[1536 + kk] + g2[1536 + kk] + g3[1536 + kk] + P.b_ih[1536 + kk] + P.b_hh[1536 + kk];
      float c = sigm_(f_) * P.c_prev[(size_t)b * kH + kk] + sigm_(i_) * tanhf(gg);
      float h = sigm_(o_) * tanhf(c);
      sm.p.hs[kl * 10 + bb] = h;
      if (jt == 0) P.cat[(size_t)b * kCatW + 3 * kM + kk] = h;
    }
    const int jg = tid & 63;
    const int bq = tid >> 6;  // one batch per wave (0..7)
    float acc = 0.f;
    for (int kc = 0; kc < 4; kc++) {
      const int k0 = kbase + kc * 64;
      const int kl0 = kc * 64;
      __syncthreads();
#pragma unroll
      for (int i = 0; i < 2; i++) {  // W tile: 64 j x 64 k
        int idx = tid + i * 512;
        int jj = idx >> 4;
        int kk = (idx & 15) * 4;
        int j = j0 + jj;
        float4 w = make_float4(0.f, 0.f, 0.f, 0.f);
        if (j < 1170)      w = *(const float4*)(P.write_W + (size_t)j * kH + k0 + kk);
        else if (j < 1572) w = *(const float4*)(P.read_W + (size_t)(j - 1170) * kH + k0 + kk);
        sm.p.Wt[(kk + 0) * 65 + jj] = w.x; sm.p.Wt[(kk + 1) * 65 + jj] = w.y;
        sm.p.Wt[(kk + 2) * 65 + jj] = w.z; sm.p.Wt[(kk + 3) * 65 + jj] = w.w;
      }
      __syncthreads();
#pragma unroll 4
      for (int k = 0; k < 64; k++)
        acc += sm.p.hs[(kl0 + k) * 10 + bq] * sm.p.Wt[k * 65 + jg];
    }
    float* pd = kh ? P.praw1 : P.praw0;
    if (j0 + jg < 1572) pd[(size_t)(b0 + bq) * kPRow + j0 + jg] = acc;
  }
  barrier_on(P.gcnt, GRID * 2);

  // ============ From here: per-batch pipeline (8 blocks per batch) ============
  const int b = bb_;
  const size_t brow = (size_t)b * kN;

  // ---- Stage S (sub 0 only): split params + sdots + zero cat[b][0:384) ----
  if (sub_ == 0) {
    const int m = tid & 127;
    const int hg = tid >> 7;  // 0..3
    const float* pr0 = P.praw0 + (size_t)b * kPRow;
    const float* pr1 = P.praw1 + (size_t)b * kPRow;
    if (tid < 384) P.cat[(size_t)b * kCatW + tid] = 0.f;
    {  // iter 0: heads {W0, W1, W2, R0}
      const bool isw = hg < 3;
      const int base = isw ? hg * 390 : 1170;
      const float* bias = isw ? (P.write_b + hg * 390) : P.read_b;
      const int slot = isw ? hg : 3;
      float kv = pr0[base + m] + pr1[base + m] + bias[m];
      if (isw) {
        P.kwb[((size_t)hg * kB + b) * kM + m] = kv;
        P.evb[((size_t)hg * kB + b) * kM + m] =
            sigm_(pr0[base + 134 + m] + pr1[base + 134 + m] + bias[134 + m]);
        P.avb[((size_t)hg * kB + b) * kM + m] =
            pr0[base + 262 + m] + pr1[base + 262 + m] + bias[262 + m];
      } else {
        P.krb[((size_t)0 * kB + b) * kM + m] = kv;
      }
      float sq = kv * kv;
#pragma unroll
      for (int mm = 1; mm < 64; mm <<= 1) sq += __shfl_xor(sq, mm, 64);
      if ((tid & 63) == 0) sm.s.nred[hg][m >> 6] = sq;
      __syncthreads();
      if (m == 0) {
        float* s = P.scal + ((size_t)slot * kB + b) * 8;
        s[0] = softplus_(pr0[base + 128] + pr1[base + 128] + bias[128]);
        s[1] = sigm_(pr0[base + 129] + pr1[base + 129] + bias[129]);
        s[2] = 1.f + softplus_(pr0[base + 133] + pr1[base + 133] + bias[133]);
        float x0 = pr0[base + 130] + pr1[base + 130] + bias[130];
        float x1 = pr0[base + 131] + pr1[base + 131] + bias[131];
        float x2 = pr0[base + 132] + pr1[base + 132] + bias[132];
        float mx = fmaxf(x0, fmaxf(x1, x2));
        float e0 = expf(x0 - mx), e1 = expf(x1 - mx), e2 = expf(x2 - mx);
        float si = 1.f / (e0 + e1 + e2);
        s[3] = e0 * si; s[4] = e1 * si; s[5] = e2 * si;
        s[6] = sqrtf(sm.s.nred[hg][0] + sm.s.nred[hg][1]);
      }
      __syncthreads();
    }
    {  // iter 1: heads {R1, R2} on hg 0,1
      const int j = (hg < 2) ? hg + 1 : 2;
      const bool act = hg < 2;
      const int base = 1170 + j * 134;
      const float* bias = P.read_b + j * 134;
      const int slot = 3 + j;
      float kv = pr0[base + m] + pr1[base + m] + bias[m];
      if (act) P.krb[((size_t)j * kB + b) * kM + m] = kv;
      float sq = kv * kv;
#pragma unroll
      for (int mm = 1; mm < 64; mm <<= 1) sq += __shfl_xor(sq, mm, 64);
      if ((tid & 63) == 0) sm.s.nred[hg][m >> 6] = sq;
      __syncthreads();
      if (m == 0 && act) {
        float* s = P.scal + ((size_t)slot * kB + b) * 8;
        s[0] = softplus_(pr0[base + 128] + pr1[base + 128] + bias[128]);
        s[1] = sigm_(pr0[base + 129] + pr1[base + 129] + bias[129]);
        s[2] = 1.f + softplus_(pr0[base + 133] + pr1[base + 133] + bias[133]);
        float x0 = pr0[base + 130] + pr1[base + 130] + bias[130];
        float x1 = pr0[base + 131] + pr1[base + 131] + bias[131];
        float x2 = pr0[base + 132] + pr1[base + 132] + bias[132];
        float mx = fmaxf(x0, fmaxf(x1, x2));
        float e0 = expf(x0 - mx), e1 = expf(x1 - mx), e2 = expf(x2 - mx);
        float si = 1.f / (e0 + e1 + e2);
        s[3] = e0 * si; s[4] = e1 * si; s[5] = e2 * si;
        s[6] = sqrtf(sm.s.nred[hg][0] + sm.s.nred[hg][1]);
      }
      __syncthreads();
    }
    // sdots: {a0.kr0, a0.kw1, a0.a0, a2.kr2, a2.a2}
    if (tid < 64) {
      const float* a0v = P.avb + ((size_t)0 * kB + b) * kM;
      const float* a2v = P.avb + ((size_t)2 * kB + b) * kM;
      const float* u[5] = {a0v, a0v, a0v, a2v, a2v};
      const float* v[5] = {P.krb + ((size_t)0 * kB + b) * kM,
                           P.kwb + ((size_t)1 * kB + b) * kM,
                           a0v,
                           P.krb + ((size_t)2 * kB + b) * kM,
                           a2v};
#pragma unroll
      for (int d = 0; d < 5; d++) {
        float s = u[d][tid] * v[d][tid] + u[d][tid + 64] * v[d][tid + 64];
#pragma unroll
        for (int mm = 1; mm < 64; mm <<= 1) s += __shfl_xor(s, mm, 64);
        if (tid == 0) P.sdot[b * 8 + d] = s;
      }
    }
  }
  barrier_on(bc, 8);

  // ---- Pass A: B0 moments (chunk = sub, 512 rows each) ----
  {
    const int chunk = sub_;
    const int lane = tid & 63, wv = tid >> 6, sub = lane >> 4, lm = lane & 15;
    const int m8 = lm * 8;
    float kw0r[8], kr0r[8], kw1r[8], a0r[8], e0r[8];
#pragma unroll
    for (int t = 0; t < 8; t++) {
      kw0r[t] = P.kwb[((size_t)0 * kB + b) * kM + m8 + t];
      kr0r[t] = P.krb[((size_t)0 * kB + b) * kM + m8 + t];
      kw1r[t] = P.kwb[((size_t)1 * kB + b) * kM + m8 + t];
      a0r[t]  = P.avb[((size_t)0 * kB + b) * kM + m8 + t];
      e0r[t]  = P.evb[((size_t)0 * kB + b) * kM + m8 + t];
    }
    const size_t bbase = (size_t)b * kN * kM;
    const int row0 = chunk * 512 + wv * 4 + sub;
    const float* base = P.bank + bbase + (size_t)row0 * kM + m8;
    float4 pA0 = *(const float4*)(base);
    float4 pA1 = *(const float4*)(base + 4);
    float4 pB0 = *(const float4*)(base + (size_t)32 * kM);
    float4 pB1 = *(const float4*)(base + (size_t)32 * kM + 4);
    for (int it = 0; it < 16; it++) {
      float v[8];
      if ((it & 1) == 0) {
        v[0]=pA0.x; v[1]=pA0.y; v[2]=pA0.z; v[3]=pA0.w; v[4]=pA1.x; v[5]=pA1.y; v[6]=pA1.z; v[7]=pA1.w;
        if (it + 2 < 16) {
          const float* np = base + (size_t)(it + 2) * 32 * kM;
          pA0 = *(const float4*)np; pA1 = *(const float4*)(np + 4);
        }
      } else {
        v[0]=pB0.x; v[1]=pB0.y; v[2]=pB0.z; v[3]=pB0.w; v[4]=pB1.x; v[5]=pB1.y; v[6]=pB1.z; v[7]=pB1.w;
        if (it + 2 < 16) {
          const float* np = base + (size_t)(it + 2) * 32 * kM;
          pB0 = *(const float4*)np; pB1 = *(const float4*)(np + 4);
        }
      }
      const int row = row0 + it * 32;
      float s[10] = {};
#pragma unroll
      for (int t = 0; t < 8; t++) {
        float be = v[t] * e0r[t];
        s[0] += v[t] * kw0r[t];
        s[1] += v[t] * v[t];
        s[2] += v[t] * kr0r[t];
        s[3] += be * kr0r[t];
        s[4] += v[t] * kw1r[t];
        s[5] += be * kw1r[t];
        s[6] += be * v[t];
        s[7] += be * be;
        s[8] += v[t] * a0r[t];
        s[9] += be * a0r[t];
      }
#pragma unroll
      for (int m = 1; m < 16; m <<= 1)
#pragma unroll
        for (int k = 0; k < 10; k++) s[k] += __shfl_xor(s[k], m, 64);
      if (lm == 0) {
        float4* dst = (float4*)(P.mA + (size_t)(brow + row) * 12);
        dst[0] = make_float4(s[0], s[1], s[2], s[3]);
        dst[1] = make_float4(s[4], s[5], s[6], s[7]);
        dst[2] = make_float4(s[8], s[9], 0.f, 0.f);
      }
    }
  }
  barrier_on(bc, 16);

  // ---- Stage A12 (subs 0,1): role0: w0 -> wr0; role1: w0(dup) -> w1 ----
  if (sub_ < 2) {
    const int role = sub_;
    float loc[8], w0r[8];
    {  // write head 0 on B0 (both roles compute; role0 stores)
      const float* sc = P.scal + ((size_t)0 * kB + b) * 8;
      const float beta = sc[0], kn = sc[6];
#pragma unroll
      for (int i = 0; i < 8; i++) {
        const float* mp = P.mA + (size_t)(brow + tid + i * TPB) * 12;
        float4 q0 = *(const float4*)mp;
        loc[i] = beta * q0.x / fmaxf(sqrtf(fmaxf(q0.y, 0.f)) * kn, 1e-8f);
      }
      addr_core8(tid, loc, sc, P.write_w_prev + brow, sm.a.wb, sm.a.red);
#pragma unroll
      for (int i = 0; i < 8; i++) {
        w0r[i] = loc[i];
        if (role == 0) P.wp0[brow + tid + i * TPB] = loc[i];
      }
    }
    if (role == 0) {  // read head 0 on B1 (expanded)
      const float* sc = P.scal + ((size_t)3 * kB + b) * 8;
      const float beta = sc[0], kn = sc[6];
      const float sa0kr0 = P.sdot[b * 8 + 0], sa0a0 = P.sdot[b * 8 + 2];
#pragma unroll
      for (int i = 0; i < 8; i++) {
        const float* mp = P.mA + (size_t)(brow + tid + i * TPB) * 12;
        float4 q0 = *(const float4*)mp;
        float4 q1 = *(const float4*)(mp + 4);
        float4 q2 = *(const float4*)(mp + 8);
        float w0 = w0r[i], w0q = w0 * w0;
        float q1v = q0.y - 2.f * w0 * q1.z + w0q * q1.w + 2.f * w0 * q2.x
                  - 2.f * w0q * q2.y + w0q * sa0a0;
        float d = q0.z - w0 * q0.w + w0 * sa0kr0;
        loc[i] = beta * d / fmaxf(sqrtf(fmaxf(q1v, 0.f)) * kn, 1e-8f);
      }
      addr_core8(tid, loc, sc, P.read_w_prev + brow, sm.a.wb, sm.a.red);
#pragma unroll
      for (int i = 0; i < 8; i++) P.wp2[brow + tid + i * TPB] = loc[i];
    } else {  // write head 1 on B1 (expanded; recompute q1v locally)
      const float* sc = P.scal + ((size_t)1 * kB + b) * 8;
      const float beta = sc[0], kn = sc[6];
      const float sa0kw1 = P.sdot[b * 8 + 1], sa0a0 = P.sdot[b * 8 + 2];
#pragma unroll
      for (int i = 0; i < 8; i++) {
        const float* mp = P.mA + (size_t)(brow + tid + i * TPB) * 12;
        float4 q0 = *(const float4*)mp;
        float4 q1 = *(const float4*)(mp + 4);
        float4 q2 = *(const float4*)(mp + 8);
        float w0 = w0r[i], w0q = w0 * w0;
        float q1v = q0.y - 2.f * w0 * q1.z + w0q * q1.w + 2.f * w0 * q2.x
                  - 2.f * w0q * q2.y + w0q * sa0a0;
        float d = q1.x - w0 * q1.y + w0 * sa0kw1;
        loc[i] = beta * d / fmaxf(sqrtf(fmaxf(q1v, 0.f)) * kn, 1e-8f);
      }
      addr_core8(tid, loc, sc, P.write_w_prev + (size_t)kWN + brow, sm.a.wb, sm.a.red);
#pragma unroll
      for (int i = 0; i < 8; i++) P.wp1[brow + tid + i * TPB] = loc[i];
    }
  }
  barrier_on(bc, 24);

  // ---- Pass B: chain(w0,w1), read0, B2 moments ----
  {
    const int chunk = sub_;
    const int lane = tid & 63, wv = tid >> 6, sub = lane >> 4, lm = lane & 15;
    const int m8 = lm * 8;
    float e0r[8], a0r[8], e1r[8], a1r[8], kr1r[8], kw2r[8], kr2r[8], e2r[8], a2r[8];
#pragma unroll
    for (int t = 0; t < 8; t++) {
      e0r[t]  = P.evb[((size_t)0 * kB + b) * kM + m8 + t];
      a0r[t]  = P.avb[((size_t)0 * kB + b) * kM + m8 + t];
      e1r[t]  = P.evb[((size_t)1 * kB + b) * kM + m8 + t];
      a1r[t]  = P.avb[((size_t)1 * kB + b) * kM + m8 + t];
      kr1r[t] = P.krb[((size_t)1 * kB + b) * kM + m8 + t];
      kw2r[t] = P.kwb[((size_t)2 * kB + b) * kM + m8 + t];
      kr2r[t] = P.krb[((size_t)2 * kB + b) * kM + m8 + t];
      e2r[t]  = P.evb[((size_t)2 * kB + b) * kM + m8 + t];
      a2r[t]  = P.avb[((size_t)2 * kB + b) * kM + m8 + t];
    }
    float racc[8] = {};
    if (tid < kM) sm.r.rl[tid] = 0.f;
    const size_t bbase = (size_t)b * kN * kM;
    const int row0 = chunk * 512 + wv * 4 + sub;
    const float* base = P.bank + bbase + (size_t)row0 * kM + m8;
    const size_t wrow = brow + row0;
    float4 pA0 = *(const float4*)(base);
    float4 pA1 = *(const float4*)(base + 4);
    float4 pB0 = *(const float4*)(base + (size_t)32 * kM);
    float4 pB1 = *(const float4*)(base + (size_t)32 * kM + 4);
    float w0A = P.wp0[wrow], w1A = P.wp1[wrow], r0A = P.wp2[wrow];
    float w0B = P.wp0[wrow + 32], w1B = P.wp1[wrow + 32], r0B = P.wp2[wrow + 32];
    for (int it = 0; it < 16; it++) {
      float v[8];
      float w0, w1, wr0;
      if ((it & 1) == 0) {
        v[0]=pA0.x; v[1]=pA0.y; v[2]=pA0.z; v[3]=pA0.w; v[4]=pA1.x; v[5]=pA1.y; v[6]=pA1.z; v[7]=pA1.w;
        w0 = w0A; w1 = w1A; wr0 = r0A;
        if (it + 2 < 16) {
          const float* np = base + (size_t)(it + 2) * 32 * kM;
          pA0 = *(const float4*)np; pA1 = *(const float4*)(np + 4);
          size_t wn = wrow + (size_t)(it + 2) * 32;
          w0A = P.wp0[wn]; w1A = P.wp1[wn]; r0A = P.wp2[wn];
        }
      } else {
        v[0]=pB0.x; v[1]=pB0.y; v[2]=pB0.z; v[3]=pB0.w; v[4]=pB1.x; v[5]=pB1.y; v[6]=pB1.z; v[7]=pB1.w;
        w0 = w0B; w1 = w1B; wr0 = r0B;
        if (it + 2 < 16) {
          const float* np = base + (size_t)(it + 2) * 32 * kM;
          pB0 = *(const float4*)np; pB1 = *(const float4*)(np + 4);
          size_t wn = wrow + (size_t)(it + 2) * 32;
          w0B = P.wp0[wn]; w1B = P.wp1[wn]; r0B = P.wp2[wn];
        }
      }
      const int row = row0 + it * 32;
#pragma unroll
      for (int t = 0; t < 8; t++) {
        v[t] += w0 * (a0r[t] - e0r[t] * v[t]);  // -> B1
        racc[t] += wr0 * v[t];                   // read0 from B1
        v[t] += w1 * (a1r[t] - e1r[t] * v[t]);  // -> B2
      }
      float s[9] = {};
#pragma unroll
      for (int t = 0; t < 8; t++) {
        float ve = v[t] * e2r[t];
        s[0] += v[t] * kr1r[t];
        s[1] += v[t] * kw2r[t];
        s[2] += v[t] * v[t];
        s[3] += v[t] * kr2r[t];
        s[4] += ve * kr2r[t];
        s[5] += ve * v[t];
        s[6] += ve * ve;
        s[7] += v[t] * a2r[t];
        s[8] += ve * a2r[t];
      }
#pragma unroll
      for (int m = 1; m < 16; m <<= 1)
#pragma unroll
        for (int k = 0; k < 9; k++) s[k] += __shfl_xor(s[k], m, 64);
      if (lm == 0) {
        float4* dst = (float4*)(P.mB + (size_t)(brow + row) * 12);
        dst[0] = make_float4(s[0], s[1], s[2], s[3]);
        dst[1] = make_float4(s[4], s[5], s[6], s[7]);
        dst[2] = make_float4(s[8], 0.f, 0.f, 0.f);
      }
    }
    __syncthreads();
#pragma unroll
    for (int t = 0; t < 8; t++) {
      racc[t] += __shfl_xor(racc[t], 16, 64);
      racc[t] += __shfl_xor(racc[t], 32, 64);
    }
    if (sub == 0) {
#pragma unroll
      for (int t = 0; t < 8; t++) atomicAdd(&sm.r.rl[m8 + t], racc[t]);
    }
    __syncthreads();
    if (tid < kM) atomicAdd(&P.cat[(size_t)b * kCatW + tid], sm.r.rl[tid]);
  }
  barrier_on(bc, 32);

  // ---- Stage A34 (subs 0,1): role0: w2 -> wr2; role1: wr1 ----
  if (sub_ < 2) {
    const int role = sub_;
    float loc[8];
    if (role == 0) {
      float w2r[8];
      {  // write head 2 on B2
        const float* sc = P.scal + ((size_t)2 * kB + b) * 8;
        const float beta = sc[0], kn = sc[6];
#pragma unroll
        for (int i = 0; i < 8; i++) {
          const float* mp = P.mB + (size_t)(brow + tid + i * TPB) * 12;
          float4 q0 = *(const float4*)mp;
          loc[i] = beta * q0.y / fmaxf(sqrtf(fmaxf(q0.z, 0.f)) * kn, 1e-8f);
        }
        addr_core8(tid, loc, sc, P.write_w_prev + (size_t)2 * kWN + brow, sm.a.wb, sm.a.red);
#pragma unroll
        for (int i = 0; i < 8; i++) {
          P.wp3[brow + tid + i * TPB] = loc[i];
          w2r[i] = loc[i];
        }
      }
      {  // read head 2 on B3 (expanded)
        const float* sc = P.scal + ((size_t)5 * kB + b) * 8;
        const float beta = sc[0], kn = sc[6];
        const float sa2kr2 = P.sdot[b * 8 + 3], sa2a2 = P.sdot[b * 8 + 4];
#pragma unroll
        for (int i = 0; i < 8; i++) {
          const float* mp = P.mB + (size_t)(brow + tid + i * TPB) * 12;
          float4 q0 = *(const float4*)mp;
          float4 q1 = *(const float4*)(mp + 4);
          float4 q2 = *(const float4*)(mp + 8);
          float w2 = w2r[i], w2q = w2 * w2;
          float q3 = q0.z - 2.f * w2 * q1.y + w2q * q1.z + 2.f * w2 * q1.w
                   - 2.f * w2q * q2.x + w2q * sa2a2;
          float d = q0.w - w2 * q1.x + w2 * sa2kr2;
          loc[i] = beta * d / fmaxf(sqrtf(fmaxf(q3, 0.f)) * kn, 1e-8f);
        }
        addr_core8(tid, loc, sc, P.read_w_prev + (size_t)2 * kWN + brow, sm.a.wb, sm.a.red);
#pragma unroll
        for (int i = 0; i < 8; i++) P.wp5[brow + tid + i * TPB] = loc[i];
      }
    } else {
      {  // read head 1 on B2 (independent of w2)
        const float* sc = P.scal + ((size_t)4 * kB + b) * 8;
        const float beta = sc[0], kn = sc[6];
#pragma unroll
        for (int i = 0; i < 8; i++) {
          const float* mp = P.mB + (size_t)(brow + tid + i * TPB) * 12;
          float4 q0 = *(const float4*)mp;
          loc[i] = beta * q0.x / fmaxf(sqrtf(fmaxf(q0.z, 0.f)) * kn, 1e-8f);
        }
        addr_core8(tid, loc, sc, P.read_w_prev + (size_t)kWN + brow, sm.a.wb, sm.a.red);
#pragma unroll
        for (int i = 0; i < 8; i++) P.wp4[brow + tid + i * TPB] = loc[i];
      }
    }
  }
  barrier_on(bc, 40);

  // ---- Pass C: chain(w0,w1,w2), read1 from B2, read2 from B3 ----
  {
    const int chunk = sub_;
    const int lane = tid & 63, wv = tid >> 6, sub = lane >> 4, lm = lane & 15;
    const int m8 = lm * 8;
    float e_r[3][8], a_r[3][8];
#pragma unroll
    for (int j = 0; j < 3; j++)
#pragma unroll
      for (int t = 0; t < 8; t++) {
        e_r[j][t] = P.evb[((size_t)j * kB + b) * kM + m8 + t];
        a_r[j][t] = P.avb[((size_t)j * kB + b) * kM + m8 + t];
      }
    float racc1[8] = {}, racc2[8] = {};
    if (tid < kM) { sm.r.rl[tid] = 0.f; sm.r.rl[kM + tid] = 0.f; }
    const size_t bbase = (size_t)b * kN * kM;
    const int row0 = chunk * 512 + wv * 4 + sub;
    const float* base = P.bank + bbase + (size_t)row0 * kM + m8;
    const size_t wrow = brow + row0;
    float4 pA0 = *(const float4*)(base);
    float4 pA1 = *(const float4*)(base + 4);
    float4 pB0 = *(const float4*)(base + (size_t)32 * kM);
    float4 pB1 = *(const float4*)(base + (size_t)32 * kM + 4);
    float c0A = P.wp0[wrow], c1A = P.wp1[wrow], c2A = P.wp3[wrow], c3A = P.wp4[wrow], c4A = P.wp5[wrow];
    float c0B = P.wp0[wrow + 32], c1B = P.wp1[wrow + 32], c2B = P.wp3[wrow + 32],
          c3B = P.wp4[wrow + 32], c4B = P.wp5[wrow + 32];
    for (int it = 0; it < 16; it++) {
      float v[8];
      float w0, w1, w2, wr1, wr2;
      if ((it & 1) == 0) {
        v[0]=pA0.x; v[1]=pA0.y; v[2]=pA0.z; v[3]=pA0.w; v[4]=pA1.x; v[5]=pA1.y; v[6]=pA1.z; v[7]=pA1.w;
        w0 = c0A; w1 = c1A; w2 = c2A; wr1 = c3A; wr2 = c4A;
        if (it + 2 < 16) {
          const float* np = base + (size_t)(it + 2) * 32 * kM;
          pA0 = *(const float4*)np; pA1 = *(const float4*)(np + 4);
          size_t wn = wrow + (size_t)(it + 2) * 32;
          c0A = P.wp0[wn]; c1A = P.wp1[wn]; c2A = P.wp3[wn]; c3A = P.wp4[wn]; c4A = P.wp5[wn];
        }
      } else {
        v[0]=pB0.x; v[1]=pB0.y; v[2]=pB0.z; v[3]=pB0.w; v[4]=pB1.x; v[5]=pB1.y; v[6]=pB1.z; v[7]=pB1.w;
        w0 = c0B; w1 = c1B; w2 = c2B; wr1 = c3B; wr2 = c4B;
        if (it + 2 < 16) {
          const float* np = base + (size_t)(it + 2) * 32 * kM;
          pB0 = *(const float4*)np; pB1 = *(const float4*)(np + 4);
          size_t wn = wrow + (size_t)(it + 2) * 32;
          c0B = P.wp0[wn]; c1B = P.wp1[wn]; c2B = P.wp3[wn]; c3B = P.wp4[wn]; c4B = P.wp5[wn];
        }
      }
#pragma unroll
      for (int t = 0; t < 8; t++) {
        v[t] += w0 * (a_r[0][t] - e_r[0][t] * v[t]);  // B1
        v[t] += w1 * (a_r[1][t] - e_r[1][t] * v[t]);  // B2
        racc1[t] += wr1 * v[t];
        v[t] += w2 * (a_r[2][t] - e_r[2][t] * v[t]);  // B3
        racc2[t] += wr2 * v[t];
      }
    }
    __syncthreads();
#pragma unroll
    for (int t = 0; t < 8; t++) {
      racc1[t] += __shfl_xor(racc1[t], 16, 64);
      racc1[t] += __shfl_xor(racc1[t], 32, 64);
      racc2[t] += __shfl_xor(racc2[t], 16, 64);
      racc2[t] += __shfl_xor(racc2[t], 32, 64);
    }
    if (sub == 0) {
#pragma unroll
      for (int t = 0; t < 8; t++) {
        atomicAdd(&sm.r.rl[m8 + t], racc1[t]);
        atomicAdd(&sm.r.rl[kM + m8 + t], racc2[t]);
      }
    }
    __syncthreads();
    if (tid < kM) {
      atomicAdd(&P.cat[(size_t)b * kCatW + kM + tid], sm.r.rl[tid]);
      atomicAdd(&P.cat[(size_t)b * kCatW + 2 * kM + tid], sm.r.rl[kM + tid]);
    }
  }
  barrier_on(bc, 48);

  // ---- Phase O: per-batch out rows (no atomics): block sub covers 32 j's ----
  {
    const int j = sub_ * 32 + (tid >> 4);
    const int ks = (tid & 15) * 56;
    const float* crow = P.cat + (size_t)b * kCatW;
    const float* wrow = P.out_W + (size_t)j * kCatW;
    float acc = 0.f;
#pragma unroll 7
    for (int k = 0; k < 56; k += 4) {
      float4 cv = *(const float4*)(crow + ks + k);
      float4 wv = *(const float4*)(wrow + ks + k);
      acc += cv.x * wv.x + cv.y * wv.y + cv.z * wv.z + cv.w * wv.w;
    }
    acc += __shfl_xor(acc, 1, 64);
    acc += __shfl_xor(acc, 2, 64);
    acc += __shfl_xor(acc, 4, 64);
    acc += __shfl_xor(acc, 8, 64);
    if ((tid & 15) == 0) P.out[(size_t)b * kO + j] = P.out_b[j] + acc;
  }
}

}  // namespace

extern "C" void kernel_launch(void* const* d_in, const int* in_sizes, int n_in,
                              void* d_out, int out_size, void* d_ws, size_t ws_size,
                              hipStream_t stream) {
  Args A_;
  A_.x            = (const float*)d_in[0];
  A_.h_prev       = (const float*)d_in[1];
  A_.c_prev       = (const float*)d_in[2];
  A_.bank         = (const float*)d_in[3];
  A_.read_w_prev  = (const float*)d_in[4];
  A_.write_w_prev = (const float*)d_in[5];
  A_.W_ih         = (const float*)d_in[6];
  A_.W_hh         = (const float*)d_in[7];
  A_.b_ih         = (const float*)d_in[8];
  A_.b_hh         = (const float*)d_in[9];
  A_.read_W       = (const float*)d_in[10];
  A_.read_b       = (const float*)d_in[11];
  A_.write_W      = (const float*)d_in[12];
  A_.write_b      = (const float*)d_in[13];
  A_.out_W        = (const float*)d_in[14];
  A_.out_b        = (const float*)d_in[15];
  A_.out = (float*)d_out;

  float* ws = (float*)d_ws;
  A_.gcnt = (unsigned*)d_ws;            // [0]: global barrier counter
  A_.bcnt = (unsigned*)d_ws + 64;       // 64 batches x 32-u32 stride (128 B each)
  float* p = ws + 4096;                 // data starts at +16 KB (zeroed region)
  A_.gates0 = p; p += (size_t)kB * kGates;
  A_.gates1 = p; p += (size_t)kB * kGates;
  A_.gates2 = p; p += (size_t)kB * kGates;
  A_.gates3 = p; p += (size_t)kB * kGates;
  A_.praw0  = p; p += (size_t)kB * kPRow;
  A_.praw1  = p; p += (size_t)kB * kPRow;
  A_.cat    = p; p += (size_t)kB * kCatW;
  A_.kwb    = p; p += (size_t)3 * kB * kM;
  A_.krb    = p; p += (size_t)3 * kB * kM;
  A_.evb    = p; p += (size_t)3 * kB * kM;
  A_.avb    = p; p += (size_t)3 * kB * kM;
  A_.scal   = p; p += (size_t)6 * kB * 8;
  A_.sdot   = p; p += (size_t)kB * 8;
  A_.wp0    = p; p += (size_t)kWN;
  A_.wp1    = p; p += (size_t)kWN;
  A_.wp2    = p; p += (size_t)kWN;
  A_.wp3    = p; p += (size_t)kWN;
  A_.wp4    = p; p += (size_t)kWN;
  A_.wp5    = p; p += (size_t)kWN;
  A_.mA     = p; p += (size_t)kWN * 12;
  A_.mB     = p; p += (size_t)kWN * 12;

  hipMemsetAsync(d_ws, 0, 16384, stream);
  mega<<<dim3(GRID), dim3(TPB), 0, stream>>>(A_);

  (void)in_sizes; (void)n_in; (void)out_size; (void)ws_size;
}

// Round 6
// 439.718 us; speedup vs baseline: 1.5287x; 1.5287x over previous
//
#include <hip/hip_runtime.h>
#include <math.h>

namespace {

constexpr int kB = 64;
constexpr int kN = 4096;
constexpr int kM = 128;
constexpr int kH = 512;
constexpr int kE = 256;
constexpr int kO = 256;
constexpr int kGates = 4 * kH;      // 2048
constexpr int kCatW = 3 * kM + kH;  // 896
constexpr int kPRow = 1600;         // padded 1572
constexpr int kWN = kB * kN;
constexpr int GRID = 256;           // 1 block/CU; launch_bounds(512,2): VGPR<=256, no spill
constexpr int TPB = 512;
constexpr float kLog2e = 1.4426950408889634f;

__device__ __forceinline__ float sigm_(float x) { return 1.f / (1.f + expf(-x)); }
__device__ __forceinline__ float softplus_(float x) { return x > 20.f ? x : log1pf(expf(x)); }

struct Args {
  const float *x, *h_prev, *c_prev, *bank, *read_w_prev, *write_w_prev;
  const float *W_ih, *W_hh, *b_ih, *b_hh, *read_W, *read_b, *write_W, *write_b, *out_W, *out_b;
  float *out;
  float *gates0, *gates1, *praw0, *praw1, *cat;
  float *kwb, *krb, *evb, *avb, *scal, *sdot;
  float *wp0, *wp1, *wp2, *wp3, *wp4, *wp5;
  float *mA, *mB;
  unsigned *gcnt;   // global barrier counter
  unsigned *bcnt;   // per-batch counters, stride 32 u32 (128 B) each
};

union SMem {
  struct { float At[64 * 20]; float Wt[64 * 65]; } g;   // gates tiles
  struct { float hs[256 * 18]; float Wt[64 * 65]; } p;  // proj: 16-batch h-slice + W tile
  struct { float wb[kN]; float red[8]; } a;             // addressing
  struct { float nred[4][2]; } s;                       // split norms
  struct { float rl[2 * kM]; } r;                       // passB/C read reduce
};

// Barrier primitive. Poll RELAXED (no per-iteration cache inv); release fence
// before arrival, acquire fence after exit. (Round-1: acquire-poll = L2 inv
// storm.) Round-5 lesson: do NOT use launch_bounds to force 2 blocks/CU here —
// the register cap (VGPR 112->64) spills ~50 regs/thread to scratch = +650 MB
// HBM traffic, 269->512us. ILP (depth-4 prefetch) beats TLP for this kernel.
__device__ __forceinline__ void barrier_on(unsigned* c, unsigned target) {
  __syncthreads();
  if (threadIdx.x == 0) {
    __builtin_amdgcn_fence(__ATOMIC_RELEASE, "agent");
    __hip_atomic_fetch_add(c, 1u, __ATOMIC_RELAXED, __HIP_MEMORY_SCOPE_AGENT);
    while (__hip_atomic_load(c, __ATOMIC_RELAXED, __HIP_MEMORY_SCOPE_AGENT) < target)
      __builtin_amdgcn_s_sleep(1);
    __builtin_amdgcn_fence(__ATOMIC_ACQUIRE, "agent");
  }
  __syncthreads();
}

// 512-thread addressing core, 8 elems/thread (N=4096)
__device__ void addr_core8(int tid, float* loc, const float* sc, const float* __restrict__ wp,
                           float* wb, float* red) {
  const float g = sc[1], r = sc[2];
  const float s0 = sc[3], s1c = sc[4], s2 = sc[5];
  const int lane = tid & 63, wid = tid >> 6;  // wid 0..7
  __syncthreads();
  float mx = loc[0];
#pragma unroll
  for (int i = 1; i < 8; i++) mx = fmaxf(mx, loc[i]);
#pragma unroll
  for (int m = 1; m < 64; m <<= 1) mx = fmaxf(mx, __shfl_xor(mx, m, 64));
  if (lane == 0) red[wid] = mx;
  __syncthreads();
  mx = red[0];
#pragma unroll
  for (int k = 1; k < 8; k++) mx = fmaxf(mx, red[k]);
  float sum = 0.f;
#pragma unroll
  for (int i = 0; i < 8; i++) { loc[i] = exp2f((loc[i] - mx) * kLog2e); sum += loc[i]; }
#pragma unroll
  for (int m = 1; m < 64; m <<= 1) sum += __shfl_xor(sum, m, 64);
  __syncthreads();
  if (lane == 0) red[wid] = sum;
  __syncthreads();
  sum = red[0];
#pragma unroll
  for (int k = 1; k < 8; k++) sum += red[k];
  const float inv = 1.f / sum;
  const float omg = 1.f - g;
#pragma unroll
  for (int i = 0; i < 8; i++) {
    int n = tid + i * TPB;
    wb[n] = loc[i] * inv + omg * wp[n];
  }
  __syncthreads();
  float ssum = 0.f;
#pragma unroll
  for (int i = 0; i < 8; i++) {
    int n = tid + i * TPB;
    float sh = s0 * wb[(n + kN - 1) & (kN - 1)] + s1c * wb[n] + s2 * wb[(n + 1) & (kN - 1)];
    float y = (sh > 0.f) ? exp2f(r * log2f(sh)) : 0.f;
    loc[i] = y;
    ssum += y;
  }
#pragma unroll
  for (int m = 1; m < 64; m <<= 1) ssum += __shfl_xor(ssum, m, 64);
  __syncthreads();
  if (lane == 0) red[wid] = ssum;
  __syncthreads();
  ssum = red[0];
#pragma unroll
  for (int k = 1; k < 8; k++) ssum += red[k];
  const float invs = 1.f / (ssum + 1e-8f);
#pragma unroll
  for (int i = 0; i < 8; i++) loc[i] *= invs;
  __syncthreads();
}

__global__ __launch_bounds__(TPB, 2) void mega(Args P) {
  const int bid = blockIdx.x;
  const int tid = threadIdx.x;
  __shared__ SMem sm;

  // Per-batch group: batch = bid & 63, member sub = bid >> 6 (0..3).
  // Group {b, b+64, b+128, b+192} shares bid%8 -> same XCD under round-robin.
  const int bb_ = bid & 63;
  const int sub_ = bid >> 6;
  unsigned* bc = P.bcnt + bb_ * 32;

  // =============== Phase G: gates GEMM, 2-way k-split (256 blocks) ===============
  {
    const int khalf = bid >> 7;
    const int unit = bid & 127;
    const int b0 = (unit >> 5) * 16;
    const int j0 = (unit & 31) * 64;
    const int jg = tid & 63;
    const int bq2 = (tid >> 6) * 2;
    float acc0 = 0.f, acc1 = 0.f;
    for (int kc6 = 0; kc6 < 6; kc6++) {
      const int kc = khalf * 6 + kc6;
      const bool isx = kc < 4;
      const float* A = isx ? P.x : P.h_prev;
      const float* W = isx ? P.W_ih : P.W_hh;
      const int lda = isx ? kE : kH;
      const int k0 = (isx ? kc : (kc - 4)) * 64;
      __syncthreads();
      {  // A tile: 16 b x 64 k
        int bb = tid >> 5;
        int kk = (tid & 31) * 2;
        float2 v = *(const float2*)(A + (size_t)(b0 + bb) * lda + k0 + kk);
        sm.g.At[(kk + 0) * 20 + bb] = v.x;
        sm.g.At[(kk + 1) * 20 + bb] = v.y;
      }
#pragma unroll
      for (int i = 0; i < 2; i++) {  // W tile: 64 j x 64 k
        int idx = tid + i * 512;
        int jj = idx >> 4;
        int kk = (idx & 15) * 4;
        float4 w = *(const float4*)(W + (size_t)(j0 + jj) * lda + k0 + kk);
        sm.g.Wt[(kk + 0) * 65 + jj] = w.x; sm.g.Wt[(kk + 1) * 65 + jj] = w.y;
        sm.g.Wt[(kk + 2) * 65 + jj] = w.z; sm.g.Wt[(kk + 3) * 65 + jj] = w.w;
      }
      __syncthreads();
#pragma unroll 4
      for (int k = 0; k < 64; k++) {
        float2 av = *(const float2*)&sm.g.At[k * 20 + bq2];
        float wv = sm.g.Wt[k * 65 + jg];
        acc0 += av.x * wv; acc1 += av.y * wv;
      }
    }
    float* gd = khalf ? P.gates1 : P.gates0;
    gd[(size_t)(b0 + bq2 + 0) * kGates + j0 + jg] = acc0;
    gd[(size_t)(b0 + bq2 + 1) * kGates + j0 + jg] = acc1;
  }
  barrier_on(P.gcnt, GRID * 1);

  // ====== Phase P: proj GEMM w/ fused h recompute, 2-way k-split (200 blocks) ======
  if (bid < 200) {
    const int kh = bid / 100;
    const int u = bid % 100;
    const int b0 = (u / 25) * 16;
    const int jt = u % 25;
    const int j0 = jt * 64;
    const int kbase = kh * 256;
    for (int i = tid; i < 16 * 256; i += TPB) {
      int bb = i >> 8, kl = i & 255;
      int kk = kbase + kl;
      int b = b0 + bb;
      const float* g0 = P.gates0 + (size_t)b * kGates;
      const float* g1 = P.gates1 + (size_t)b * kGates;
      float i_ = g0[kk]        + g1[kk]        + P.b_ih[kk]        + P.b_hh[kk];
      float f_ = g0[512 + kk]  + g1[512 + kk]  + P.b_ih[512 + kk]  + P.b_hh[512 + kk];
      float gg = g0[1024 + kk] + g1[1024 + kk] + P.b_ih[1024 + kk] + P.b_hh[1024 + kk];
      float o_ = g0[1536 + kk] + g1[1536 + kk] + P.b_ih[1536 + kk] + P.b_hh[1536 + kk];
      float c = sigm_(f_) * P.c_prev[(size_t)b * kH + kk] + sigm_(i_) * tanhf(gg);
      float h = sigm_(o_) * tanhf(c);
      sm.p.hs[kl * 18 + bb] = h;
      if (jt == 0) P.cat[(size_t)b * kCatW + 3 * kM + kk] = h;
    }
    const int jg = tid & 63;
    const int bq2 = (tid >> 6) * 2;
    float acc0 = 0.f, acc1 = 0.f;
    for (int kc = 0; kc < 4; kc++) {
      const int k0 = kbase + kc * 64;
      const int kl0 = kc * 64;
      __syncthreads();
#pragma unroll
      for (int i = 0; i < 2; i++) {
        int idx = tid + i * 512;
        int jj = idx >> 4;
        int kk = (idx & 15) * 4;
        int j = j0 + jj;
        float4 w = make_float4(0.f, 0.f, 0.f, 0.f);
        if (j < 1170)      w = *(const float4*)(P.write_W + (size_t)j * kH + k0 + kk);
        else if (j < 1572) w = *(const float4*)(P.read_W + (size_t)(j - 1170) * kH + k0 + kk);
        sm.p.Wt[(kk + 0) * 65 + jj] = w.x; sm.p.Wt[(kk + 1) * 65 + jj] = w.y;
        sm.p.Wt[(kk + 2) * 65 + jj] = w.z; sm.p.Wt[(kk + 3) * 65 + jj] = w.w;
      }
      __syncthreads();
#pragma unroll 4
      for (int k = 0; k < 64; k++) {
        float2 av = *(const float2*)&sm.p.hs[(kl0 + k) * 18 + bq2];
        float wv = sm.p.Wt[k * 65 + jg];
        acc0 += av.x * wv; acc1 += av.y * wv;
      }
    }
    float* pd = kh ? P.praw1 : P.praw0;
    if (j0 + jg < 1572) {
      pd[(size_t)(b0 + bq2 + 0) * kPRow + j0 + jg] = acc0;
      pd[(size_t)(b0 + bq2 + 1) * kPRow + j0 + jg] = acc1;
    }
  }
  barrier_on(P.gcnt, GRID * 2);

  // ============ From here: per-batch pipeline (4 blocks per batch) ============
  const int b = bb_;
  const size_t brow = (size_t)b * kN;

  // ---- Stage S (sub 0 only): split params + sdots + zero cat[b][0:384) ----
  if (sub_ == 0) {
    const int m = tid & 127;
    const int hg = tid >> 7;  // 0..3
    const float* pr0 = P.praw0 + (size_t)b * kPRow;
    const float* pr1 = P.praw1 + (size_t)b * kPRow;
    if (tid < 384) P.cat[(size_t)b * kCatW + tid] = 0.f;
    {  // iter 0: heads {W0, W1, W2, R0}
      const bool isw = hg < 3;
      const int base = isw ? hg * 390 : 1170;
      const float* bias = isw ? (P.write_b + hg * 390) : P.read_b;
      const int slot = isw ? hg : 3;
      float kv = pr0[base + m] + pr1[base + m] + bias[m];
      if (isw) {
        P.kwb[((size_t)hg * kB + b) * kM + m] = kv;
        P.evb[((size_t)hg * kB + b) * kM + m] =
            sigm_(pr0[base + 134 + m] + pr1[base + 134 + m] + bias[134 + m]);
        P.avb[((size_t)hg * kB + b) * kM + m] =
            pr0[base + 262 + m] + pr1[base + 262 + m] + bias[262 + m];
      } else {
        P.krb[((size_t)0 * kB + b) * kM + m] = kv;
      }
      float sq = kv * kv;
#pragma unroll
      for (int mm = 1; mm < 64; mm <<= 1) sq += __shfl_xor(sq, mm, 64);
      if ((tid & 63) == 0) sm.s.nred[hg][m >> 6] = sq;
      __syncthreads();
      if (m == 0) {
        float* s = P.scal + ((size_t)slot * kB + b) * 8;
        s[0] = softplus_(pr0[base + 128] + pr1[base + 128] + bias[128]);
        s[1] = sigm_(pr0[base + 129] + pr1[base + 129] + bias[129]);
        s[2] = 1.f + softplus_(pr0[base + 133] + pr1[base + 133] + bias[133]);
        float x0 = pr0[base + 130] + pr1[base + 130] + bias[130];
        float x1 = pr0[base + 131] + pr1[base + 131] + bias[131];
        float x2 = pr0[base + 132] + pr1[base + 132] + bias[132];
        float mx = fmaxf(x0, fmaxf(x1, x2));
        float e0 = expf(x0 - mx), e1 = expf(x1 - mx), e2 = expf(x2 - mx);
        float si = 1.f / (e0 + e1 + e2);
        s[3] = e0 * si; s[4] = e1 * si; s[5] = e2 * si;
        s[6] = sqrtf(sm.s.nred[hg][0] + sm.s.nred[hg][1]);
      }
      __syncthreads();
    }
    {  // iter 1: heads {R1, R2} on hg 0,1
      const int j = (hg < 2) ? hg + 1 : 2;
      const bool act = hg < 2;
      const int base = 1170 + j * 134;
      const float* bias = P.read_b + j * 134;
      const int slot = 3 + j;
      float kv = pr0[base + m] + pr1[base + m] + bias[m];
      if (act) P.krb[((size_t)j * kB + b) * kM + m] = kv;
      float sq = kv * kv;
#pragma unroll
      for (int mm = 1; mm < 64; mm <<= 1) sq += __shfl_xor(sq, mm, 64);
      if ((tid & 63) == 0) sm.s.nred[hg][m >> 6] = sq;
      __syncthreads();
      if (m == 0 && act) {
        float* s = P.scal + ((size_t)slot * kB + b) * 8;
        s[0] = softplus_(pr0[base + 128] + pr1[base + 128] + bias[128]);
        s[1] = sigm_(pr0[base + 129] + pr1[base + 129] + bias[129]);
        s[2] = 1.f + softplus_(pr0[base + 133] + pr1[base + 133] + bias[133]);
        float x0 = pr0[base + 130] + pr1[base + 130] + bias[130];
        float x1 = pr0[base + 131] + pr1[base + 131] + bias[131];
        float x2 = pr0[base + 132] + pr1[base + 132] + bias[132];
        float mx = fmaxf(x0, fmaxf(x1, x2));
        float e0 = expf(x0 - mx), e1 = expf(x1 - mx), e2 = expf(x2 - mx);
        float si = 1.f / (e0 + e1 + e2);
        s[3] = e0 * si; s[4] = e1 * si; s[5] = e2 * si;
        s[6] = sqrtf(sm.s.nred[hg][0] + sm.s.nred[hg][1]);
      }
      __syncthreads();
    }
    // sdots: {a0.kr0, a0.kw1, a0.a0, a2.kr2, a2.a2}
    if (tid < 64) {
      const float* a0v = P.avb + ((size_t)0 * kB + b) * kM;
      const float* a2v = P.avb + ((size_t)2 * kB + b) * kM;
      const float* u[5] = {a0v, a0v, a0v, a2v, a2v};
      const float* v[5] = {P.krb + ((size_t)0 * kB + b) * kM,
                           P.kwb + ((size_t)1 * kB + b) * kM,
                           a0v,
                           P.krb + ((size_t)2 * kB + b) * kM,
                           a2v};
#pragma unroll
      for (int d = 0; d < 5; d++) {
        float s = u[d][tid] * v[d][tid] + u[d][tid + 64] * v[d][tid + 64];
#pragma unroll
        for (int mm = 1; mm < 64; mm <<= 1) s += __shfl_xor(s, mm, 64);
        if (tid == 0) P.sdot[b * 8 + d] = s;
      }
    }
  }
  barrier_on(bc, 4);

  // ---- Pass A: B0 moments, depth-4 prefetch pipeline ----
  {
    const int chunk = sub_;
    const int lane = tid & 63, wv = tid >> 6, sub = lane >> 4, lm = lane & 15;
    const int m8 = lm * 8;
    float kw0r[8], kr0r[8], kw1r[8], a0r[8], e0r[8];
#pragma unroll
    for (int t = 0; t < 8; t++) {
      kw0r[t] = P.kwb[((size_t)0 * kB + b) * kM + m8 + t];
      kr0r[t] = P.krb[((size_t)0 * kB + b) * kM + m8 + t];
      kw1r[t] = P.kwb[((size_t)1 * kB + b) * kM + m8 + t];
      a0r[t]  = P.avb[((size_t)0 * kB + b) * kM + m8 + t];
      e0r[t]  = P.evb[((size_t)0 * kB + b) * kM + m8 + t];
    }
    const size_t bbase = (size_t)b * kN * kM;
    const int row0 = chunk * 1024 + wv * 4 + sub;
    const float* base = P.bank + bbase + (size_t)row0 * kM + m8;

#define MOM_A(VA, VB, ITV)                                                     \
    {                                                                          \
      float v[8] = {VA.x, VA.y, VA.z, VA.w, VB.x, VB.y, VB.z, VB.w};           \
      float s[10] = {};                                                        \
      _Pragma("unroll") for (int t = 0; t < 8; t++) {                          \
        float be = v[t] * e0r[t];                                              \
        s[0] += v[t] * kw0r[t]; s[1] += v[t] * v[t];                           \
        s[2] += v[t] * kr0r[t]; s[3] += be * kr0r[t];                          \
        s[4] += v[t] * kw1r[t]; s[5] += be * kw1r[t];                          \
        s[6] += be * v[t];      s[7] += be * be;                               \
        s[8] += v[t] * a0r[t];  s[9] += be * a0r[t];                           \
      }                                                                        \
      _Pragma("unroll") for (int m = 1; m < 16; m <<= 1)                       \
        _Pragma("unroll") for (int k = 0; k < 10; k++)                         \
          s[k] += __shfl_xor(s[k], m, 64);                                     \
      if (lm == 0) {                                                           \
        float4* dst = (float4*)(P.mA + (size_t)(brow + row0 + (ITV) * 32) * 12); \
        dst[0] = make_float4(s[0], s[1], s[2], s[3]);                          \
        dst[1] = make_float4(s[4], s[5], s[6], s[7]);                          \
        dst[2] = make_float4(s[8], s[9], 0.f, 0.f);                            \
      }                                                                        \
    }

    float4 q0a = *(const float4*)(base);
    float4 q0b = *(const float4*)(base + 4);
    float4 q1a = *(const float4*)(base + (size_t)32 * kM);
    float4 q1b = *(const float4*)(base + (size_t)32 * kM + 4);
    float4 q2a = *(const float4*)(base + (size_t)64 * kM);
    float4 q2b = *(const float4*)(base + (size_t)64 * kM + 4);
    float4 q3a = *(const float4*)(base + (size_t)96 * kM);
    float4 q3b = *(const float4*)(base + (size_t)96 * kM + 4);
    for (int it = 0; it < 32; it += 4) {
      MOM_A(q0a, q0b, it);
      if (it + 4 < 32) { const float* np = base + (size_t)(it + 4) * 32 * kM;
                         q0a = *(const float4*)np; q0b = *(const float4*)(np + 4); }
      MOM_A(q1a, q1b, it + 1);
      if (it + 5 < 32) { const float* np = base + (size_t)(it + 5) * 32 * kM;
                         q1a = *(const float4*)np; q1b = *(const float4*)(np + 4); }
      MOM_A(q2a, q2b, it + 2);
      if (it + 6 < 32) { const float* np = base + (size_t)(it + 6) * 32 * kM;
                         q2a = *(const float4*)np; q2b = *(const float4*)(np + 4); }
      MOM_A(q3a, q3b, it + 3);
      if (it + 7 < 32) { const float* np = base + (size_t)(it + 7) * 32 * kM;
                         q3a = *(const float4*)np; q3b = *(const float4*)(np + 4); }
    }
#undef MOM_A
  }
  barrier_on(bc, 8);

  // ---- Stage A12 (subs 0,1): role0: w0 -> wr0; role1: w0(dup) -> w1 ----
  if (sub_ < 2) {
    const int role = sub_;
    float loc[8], w0r[8];
    {  // write head 0 on B0 (both roles compute; role0 stores)
      const float* sc = P.scal + ((size_t)0 * kB + b) * 8;
      const float beta = sc[0], kn = sc[6];
#pragma unroll
      for (int i = 0; i < 8; i++) {
        const float* mp = P.mA + (size_t)(brow + tid + i * TPB) * 12;
        float4 q0 = *(const float4*)mp;
        loc[i] = beta * q0.x / fmaxf(sqrtf(fmaxf(q0.y, 0.f)) * kn, 1e-8f);
      }
      addr_core8(tid, loc, sc, P.write_w_prev + brow, sm.a.wb, sm.a.red);
#pragma unroll
      for (int i = 0; i < 8; i++) {
        w0r[i] = loc[i];
        if (role == 0) P.wp0[brow + tid + i * TPB] = loc[i];
      }
    }
    if (role == 0) {  // read head 0 on B1 (expanded)
      const float* sc = P.scal + ((size_t)3 * kB + b) * 8;
      const float beta = sc[0], kn = sc[6];
      const float sa0kr0 = P.sdot[b * 8 + 0], sa0a0 = P.sdot[b * 8 + 2];
#pragma unroll
      for (int i = 0; i < 8; i++) {
        const float* mp = P.mA + (size_t)(brow + tid + i * TPB) * 12;
        float4 q0 = *(const float4*)mp;
        float4 q1 = *(const float4*)(mp + 4);
        float4 q2 = *(const float4*)(mp + 8);
        float w0 = w0r[i], w0q = w0 * w0;
        float q1v = q0.y - 2.f * w0 * q1.z + w0q * q1.w + 2.f * w0 * q2.x
                  - 2.f * w0q * q2.y + w0q * sa0a0;
        float d = q0.z - w0 * q0.w + w0 * sa0kr0;
        loc[i] = beta * d / fmaxf(sqrtf(fmaxf(q1v, 0.f)) * kn, 1e-8f);
      }
      addr_core8(tid, loc, sc, P.read_w_prev + brow, sm.a.wb, sm.a.red);
#pragma unroll
      for (int i = 0; i < 8; i++) P.wp2[brow + tid + i * TPB] = loc[i];
    } else {  // write head 1 on B1 (expanded; recompute q1v locally)
      const float* sc = P.scal + ((size_t)1 * kB + b) * 8;
      const float beta = sc[0], kn = sc[6];
      const float sa0kw1 = P.sdot[b * 8 + 1], sa0a0 = P.sdot[b * 8 + 2];
#pragma unroll
      for (int i = 0; i < 8; i++) {
        const float* mp = P.mA + (size_t)(brow + tid + i * TPB) * 12;
        float4 q0 = *(const float4*)mp;
        float4 q1 = *(const float4*)(mp + 4);
        float4 q2 = *(const float4*)(mp + 8);
        float w0 = w0r[i], w0q = w0 * w0;
        float q1v = q0.y - 2.f * w0 * q1.z + w0q * q1.w + 2.f * w0 * q2.x
                  - 2.f * w0q * q2.y + w0q * sa0a0;
        float d = q1.x - w0 * q1.y + w0 * sa0kw1;
        loc[i] = beta * d / fmaxf(sqrtf(fmaxf(q1v, 0.f)) * kn, 1e-8f);
      }
      addr_core8(tid, loc, sc, P.write_w_prev + (size_t)kWN + brow, sm.a.wb, sm.a.red);
#pragma unroll
      for (int i = 0; i < 8; i++) P.wp1[brow + tid + i * TPB] = loc[i];
    }
  }
  barrier_on(bc, 12);

  // ---- Pass B: chain(w0,w1), read0, B2 moments, depth-4 prefetch ----
  {
    const int chunk = sub_;
    const int lane = tid & 63, wv = tid >> 6, sub = lane >> 4, lm = lane & 15;
    const int m8 = lm * 8;
    float e0r[8], a0r[8], e1r[8], a1r[8], kr1r[8], kw2r[8], kr2r[8], e2r[8], a2r[8];
#pragma unroll
    for (int t = 0; t < 8; t++) {
      e0r[t]  = P.evb[((size_t)0 * kB + b) * kM + m8 + t];
      a0r[t]  = P.avb[((size_t)0 * kB + b) * kM + m8 + t];
      e1r[t]  = P.evb[((size_t)1 * kB + b) * kM + m8 + t];
      a1r[t]  = P.avb[((size_t)1 * kB + b) * kM + m8 + t];
      kr1r[t] = P.krb[((size_t)1 * kB + b) * kM + m8 + t];
      kw2r[t] = P.kwb[((size_t)2 * kB + b) * kM + m8 + t];
      kr2r[t] = P.krb[((size_t)2 * kB + b) * kM + m8 + t];
      e2r[t]  = P.evb[((size_t)2 * kB + b) * kM + m8 + t];
      a2r[t]  = P.avb[((size_t)2 * kB + b) * kM + m8 + t];
    }
    float racc[8] = {};
    if (tid < kM) sm.r.rl[tid] = 0.f;
    const size_t bbase = (size_t)b * kN * kM;
    const int row0 = chunk * 1024 + wv * 4 + sub;
    const float* base = P.bank + bbase + (size_t)row0 * kM + m8;
    const size_t wrow = brow + row0;

#define MOM_B(VA, VB, W0V, W1V, R0V, ITV)                                      \
    {                                                                          \
      float v[8] = {VA.x, VA.y, VA.z, VA.w, VB.x, VB.y, VB.z, VB.w};           \
      _Pragma("unroll") for (int t = 0; t < 8; t++) {                          \
        v[t] += (W0V) * (a0r[t] - e0r[t] * v[t]);                              \
        racc[t] += (R0V) * v[t];                                               \
        v[t] += (W1V) * (a1r[t] - e1r[t] * v[t]);                              \
      }                                                                        \
      float s[9] = {};                                                         \
      _Pragma("unroll") for (int t = 0; t < 8; t++) {                          \
        float ve = v[t] * e2r[t];                                              \
        s[0] += v[t] * kr1r[t]; s[1] += v[t] * kw2r[t];                        \
        s[2] += v[t] * v[t];    s[3] += v[t] * kr2r[t];                        \
        s[4] += ve * kr2r[t];   s[5] += ve * v[t];                             \
        s[6] += ve * ve;        s[7] += v[t] * a2r[t];                         \
        s[8] += ve * a2r[t];                                                   \
      }                                                                        \
      _Pragma("unroll") for (int m = 1; m < 16; m <<= 1)                       \
        _Pragma("unroll") for (int k = 0; k < 9; k++)                          \
          s[k] += __shfl_xor(s[k], m, 64);                                     \
      if (lm == 0) {                                                           \
        float4* dst = (float4*)(P.mB + (size_t)(brow + row0 + (ITV) * 32) * 12); \
        dst[0] = make_float4(s[0], s[1], s[2], s[3]);                          \
        dst[1] = make_float4(s[4], s[5], s[6], s[7]);                          \
        dst[2] = make_float4(s[8], 0.f, 0.f, 0.f);                             \
      }                                                                        \
    }

    float4 q0a = *(const float4*)(base);
    float4 q0b = *(const float4*)(base + 4);
    float4 q1a = *(const float4*)(base + (size_t)32 * kM);
    float4 q1b = *(const float4*)(base + (size_t)32 * kM + 4);
    float4 q2a = *(const float4*)(base + (size_t)64 * kM);
    float4 q2b = *(const float4*)(base + (size_t)64 * kM + 4);
    float4 q3a = *(const float4*)(base + (size_t)96 * kM);
    float4 q3b = *(const float4*)(base + (size_t)96 * kM + 4);
    float w00 = P.wp0[wrow],      w10 = P.wp1[wrow],      r00 = P.wp2[wrow];
    float w01 = P.wp0[wrow + 32], w11 = P.wp1[wrow + 32], r01 = P.wp2[wrow + 32];
    float w02 = P.wp0[wrow + 64], w12 = P.wp1[wrow + 64], r02 = P.wp2[wrow + 64];
    float w03 = P.wp0[wrow + 96], w13 = P.wp1[wrow + 96], r03 = P.wp2[wrow + 96];
    for (int it = 0; it < 32; it += 4) {
      MOM_B(q0a, q0b, w00, w10, r00, it);
      if (it + 4 < 32) { const float* np = base + (size_t)(it + 4) * 32 * kM;
                         q0a = *(const float4*)np; q0b = *(const float4*)(np + 4);
                         size_t wn = wrow + (size_t)(it + 4) * 32;
                         w00 = P.wp0[wn]; w10 = P.wp1[wn]; r00 = P.wp2[wn]; }
      MOM_B(q1a, q1b, w01, w11, r01, it + 1);
      if (it + 5 < 32) { const float* np = base + (size_t)(it + 5) * 32 * kM;
                         q1a = *(const float4*)np; q1b = *(const float4*)(np + 4);
                         size_t wn = wrow + (size_t)(it + 5) * 32;
                         w01 = P.wp0[wn]; w11 = P.wp1[wn]; r01 = P.wp2[wn]; }
      MOM_B(q2a, q2b, w02, w12, r02, it + 2);
      if (it + 6 < 32) { const float* np = base + (size_t)(it + 6) * 32 * kM;
                         q2a = *(const float4*)np; q2b = *(const float4*)(np + 4);
                         size_t wn = wrow + (size_t)(it + 6) * 32;
                         w02 = P.wp0[wn]; w12 = P.wp1[wn]; r02 = P.wp2[wn]; }
      MOM_B(q3a, q3b, w03, w13, r03, it + 3);
      if (it + 7 < 32) { const float* np = base + (size_t)(it + 7) * 32 * kM;
                         q3a = *(const float4*)np; q3b = *(const float4*)(np + 4);
                         size_t wn = wrow + (size_t)(it + 7) * 32;
                         w03 = P.wp0[wn]; w13 = P.wp1[wn]; r03 = P.wp2[wn]; }
    }
#undef MOM_B
    __syncthreads();
#pragma unroll
    for (int t = 0; t < 8; t++) {
      racc[t] += __shfl_xor(racc[t], 16, 64);
      racc[t] += __shfl_xor(racc[t], 32, 64);
    }
    if (sub == 0) {
#pragma unroll
      for (int t = 0; t < 8; t++) atomicAdd(&sm.r.rl[m8 + t], racc[t]);
    }
    __syncthreads();
    if (tid < kM) atomicAdd(&P.cat[(size_t)b * kCatW + tid], sm.r.rl[tid]);
  }
  barrier_on(bc, 16);

  // ---- Stage A34 (subs 0,1): role0: w2 -> wr2; role1: wr1 ----
  if (sub_ < 2) {
    const int role = sub_;
    float loc[8];
    if (role == 0) {
      float w2r[8];
      {  // write head 2 on B2
        const float* sc = P.scal + ((size_t)2 * kB + b) * 8;
        const float beta = sc[0], kn = sc[6];
#pragma unroll
        for (int i = 0; i < 8; i++) {
          const float* mp = P.mB + (size_t)(brow + tid + i * TPB) * 12;
          float4 q0 = *(const float4*)mp;
          loc[i] = beta * q0.y / fmaxf(sqrtf(fmaxf(q0.z, 0.f)) * kn, 1e-8f);
        }
        addr_core8(tid, loc, sc, P.write_w_prev + (size_t)2 * kWN + brow, sm.a.wb, sm.a.red);
#pragma unroll
        for (int i = 0; i < 8; i++) {
          P.wp3[brow + tid + i * TPB] = loc[i];
          w2r[i] = loc[i];
        }
      }
      {  // read head 2 on B3 (expanded)
        const float* sc = P.scal + ((size_t)5 * kB + b) * 8;
        const float beta = sc[0], kn = sc[6];
        const float sa2kr2 = P.sdot[b * 8 + 3], sa2a2 = P.sdot[b * 8 + 4];
#pragma unroll
        for (int i = 0; i < 8; i++) {
          const float* mp = P.mB + (size_t)(brow + tid + i * TPB) * 12;
          float4 q0 = *(const float4*)mp;
          float4 q1 = *(const float4*)(mp + 4);
          float4 q2 = *(const float4*)(mp + 8);
          float w2 = w2r[i], w2q = w2 * w2;
          float q3 = q0.z - 2.f * w2 * q1.y + w2q * q1.z + 2.f * w2 * q1.w
                   - 2.f * w2q * q2.x + w2q * sa2a2;
          float d = q0.w - w2 * q1.x + w2 * sa2kr2;
          loc[i] = beta * d / fmaxf(sqrtf(fmaxf(q3, 0.f)) * kn, 1e-8f);
        }
        addr_core8(tid, loc, sc, P.read_w_prev + (size_t)2 * kWN + brow, sm.a.wb, sm.a.red);
#pragma unroll
        for (int i = 0; i < 8; i++) P.wp5[brow + tid + i * TPB] = loc[i];
      }
    } else {
      {  // read head 1 on B2 (independent of w2)
        const float* sc = P.scal + ((size_t)4 * kB + b) * 8;
        const float beta = sc[0], kn = sc[6];
#pragma unroll
        for (int i = 0; i < 8; i++) {
          const float* mp = P.mB + (size_t)(brow + tid + i * TPB) * 12;
          float4 q0 = *(const float4*)mp;
          loc[i] = beta * q0.x / fmaxf(sqrtf(fmaxf(q0.z, 0.f)) * kn, 1e-8f);
        }
        addr_core8(tid, loc, sc, P.read_w_prev + (size_t)kWN + brow, sm.a.wb, sm.a.red);
#pragma unroll
        for (int i = 0; i < 8; i++) P.wp4[brow + tid + i * TPB] = loc[i];
      }
    }
  }
  barrier_on(bc, 20);

  // ---- Pass C: chain(w0,w1,w2), read1 from B2, read2 from B3, depth-4 ----
  {
    const int chunk = sub_;
    const int lane = tid & 63, wv = tid >> 6, sub = lane >> 4, lm = lane & 15;
    const int m8 = lm * 8;
    float e_r[3][8], a_r[3][8];
#pragma unroll
    for (int j = 0; j < 3; j++)
#pragma unroll
      for (int t = 0; t < 8; t++) {
        e_r[j][t] = P.evb[((size_t)j * kB + b) * kM + m8 + t];
        a_r[j][t] = P.avb[((size_t)j * kB + b) * kM + m8 + t];
      }
    float racc1[8] = {}, racc2[8] = {};
    if (tid < kM) { sm.r.rl[tid] = 0.f; sm.r.rl[kM + tid] = 0.f; }
    const size_t bbase = (size_t)b * kN * kM;
    const int row0 = chunk * 1024 + wv * 4 + sub;
    const float* base = P.bank + bbase + (size_t)row0 * kM + m8;
    const size_t wrow = brow + row0;

#define MOM_C(VA, VB, W0V, W1V, W2V, R1V, R2V)                                 \
    {                                                                          \
      float v[8] = {VA.x, VA.y, VA.z, VA.w, VB.x, VB.y, VB.z, VB.w};           \
      _Pragma("unroll") for (int t = 0; t < 8; t++) {                          \
        v[t] += (W0V) * (a_r[0][t] - e_r[0][t] * v[t]);                        \
        v[t] += (W1V) * (a_r[1][t] - e_r[1][t] * v[t]);                        \
        racc1[t] += (R1V) * v[t];                                              \
        v[t] += (W2V) * (a_r[2][t] - e_r[2][t] * v[t]);                        \
        racc2[t] += (R2V) * v[t];                                              \
      }                                                                        \
    }

    float4 q0a = *(const float4*)(base);
    float4 q0b = *(const float4*)(base + 4);
    float4 q1a = *(const float4*)(base + (size_t)32 * kM);
    float4 q1b = *(const float4*)(base + (size_t)32 * kM + 4);
    float4 q2a = *(const float4*)(base + (size_t)64 * kM);
    float4 q2b = *(const float4*)(base + (size_t)64 * kM + 4);
    float4 q3a = *(const float4*)(base + (size_t)96 * kM);
    float4 q3b = *(const float4*)(base + (size_t)96 * kM + 4);
    float c00 = P.wp0[wrow],      c10 = P.wp1[wrow],      c20 = P.wp3[wrow],
          c30 = P.wp4[wrow],      c40 = P.wp5[wrow];
    float c01 = P.wp0[wrow + 32], c11 = P.wp1[wrow + 32], c21 = P.wp3[wrow + 32],
          c31 = P.wp4[wrow + 32], c41 = P.wp5[wrow + 32];
    float c02 = P.wp0[wrow + 64], c12 = P.wp1[wrow + 64], c22 = P.wp3[wrow + 64],
          c32 = P.wp4[wrow + 64], c42 = P.wp5[wrow + 64];
    float c03 = P.wp0[wrow + 96], c13 = P.wp1[wrow + 96], c23 = P.wp3[wrow + 96],
          c33 = P.wp4[wrow + 96], c43 = P.wp5[wrow + 96];
    for (int it = 0; it < 32; it += 4) {
      MOM_C(q0a, q0b, c00, c10, c20, c30, c40);
      if (it + 4 < 32) { const float* np = base + (size_t)(it + 4) * 32 * kM;
                         q0a = *(const float4*)np; q0b = *(const float4*)(np + 4);
                         size_t wn = wrow + (size_t)(it + 4) * 32;
                         c00 = P.wp0[wn]; c10 = P.wp1[wn]; c20 = P.wp3[wn];
                         c30 = P.wp4[wn]; c40 = P.wp5[wn]; }
      MOM_C(q1a, q1b, c01, c11, c21, c31, c41);
      if (it + 5 < 32) { const float* np = base + (size_t)(it + 5) * 32 * kM;
                         q1a = *(const float4*)np; q1b = *(const float4*)(np + 4);
                         size_t wn = wrow + (size_t)(it + 5) * 32;
                         c01 = P.wp0[wn]; c11 = P.wp1[wn]; c21 = P.wp3[wn];
                         c31 = P.wp4[wn]; c41 = P.wp5[wn]; }
      MOM_C(q2a, q2b, c02, c12, c22, c32, c42);
      if (it + 6 < 32) { const float* np = base + (size_t)(it + 6) * 32 * kM;
                         q2a = *(const float4*)np; q2b = *(const float4*)(np + 4);
                         size_t wn = wrow + (size_t)(it + 6) * 32;
                         c02 = P.wp0[wn]; c12 = P.wp1[wn]; c22 = P.wp3[wn];
                         c32 = P.wp4[wn]; c42 = P.wp5[wn]; }
      MOM_C(q3a, q3b, c03, c13, c23, c33, c43);
      if (it + 7 < 32) { const float* np = base + (size_t)(it + 7) * 32 * kM;
                         q3a = *(const float4*)np; q3b = *(const float4*)(np + 4);
                         size_t wn = wrow + (size_t)(it + 7) * 32;
                         c03 = P.wp0[wn]; c13 = P.wp1[wn]; c23 = P.wp3[wn];
                         c33 = P.wp4[wn]; c43 = P.wp5[wn]; }
    }
#undef MOM_C
    __syncthreads();
#pragma unroll
    for (int t = 0; t < 8; t++) {
      racc1[t] += __shfl_xor(racc1[t], 16, 64);
      racc1[t] += __shfl_xor(racc1[t], 32, 64);
      racc2[t] += __shfl_xor(racc2[t], 16, 64);
      racc2[t] += __shfl_xor(racc2[t], 32, 64);
    }
    if (sub == 0) {
#pragma unroll
      for (int t = 0; t < 8; t++) {
        atomicAdd(&sm.r.rl[m8 + t], racc1[t]);
        atomicAdd(&sm.r.rl[kM + m8 + t], racc2[t]);
      }
    }
    __syncthreads();
    if (tid < kM) {
      atomicAdd(&P.cat[(size_t)b * kCatW + kM + tid], sm.r.rl[tid]);
      atomicAdd(&P.cat[(size_t)b * kCatW + 2 * kM + tid], sm.r.rl[kM + tid]);
    }
  }
  barrier_on(bc, 24);

  // ---- Phase O: per-batch out rows (no atomics): block sub covers 64 j's ----
  {
    const int j = sub_ * 64 + (tid >> 3);
    const int ks = (tid & 7) * 112;
    const float* crow = P.cat + (size_t)b * kCatW;
    const float* wrow = P.out_W + (size_t)j * kCatW;
    float acc = 0.f;
#pragma unroll 7
    for (int k = 0; k < 112; k += 4) {
      float4 cv = *(const float4*)(crow + ks + k);
      float4 wv = *(const float4*)(wrow + ks + k);
      acc += cv.x * wv.x + cv.y * wv.y + cv.z * wv.z + cv.w * wv.w;
    }
    acc += __shfl_xor(acc, 1, 64);
    acc += __shfl_xor(acc, 2, 64);
    acc += __shfl_xor(acc, 4, 64);
    if ((tid & 7) == 0) P.out[(size_t)b * kO + j] = P.out_b[j] + acc;
  }
}

}  // namespace

extern "C" void kernel_launch(void* const* d_in, const int* in_sizes, int n_in,
                              void* d_out, int out_size, void* d_ws, size_t ws_size,
                              hipStream_t stream) {
  Args A_;
  A_.x            = (const float*)d_in[0];
  A_.h_prev       = (const float*)d_in[1];
  A_.c_prev       = (const float*)d_in[2];
  A_.bank         = (const float*)d_in[3];
  A_.read_w_prev  = (const float*)d_in[4];
  A_.write_w_prev = (const float*)d_in[5];
  A_.W_ih         = (const float*)d_in[6];
  A_.W_hh         = (const float*)d_in[7];
  A_.b_ih         = (const float*)d_in[8];
  A_.b_hh         = (const float*)d_in[9];
  A_.read_W       = (const float*)d_in[10];
  A_.read_b       = (const float*)d_in[11];
  A_.write_W      = (const float*)d_in[12];
  A_.write_b      = (const float*)d_in[13];
  A_.out_W        = (const float*)d_in[14];
  A_.out_b        = (const float*)d_in[15];
  A_.out = (float*)d_out;

  float* ws = (float*)d_ws;
  A_.gcnt = (unsigned*)d_ws;            // [0]: global barrier counter
  A_.bcnt = (unsigned*)d_ws + 64;       // 64 batches x 32-u32 stride (128 B each)
  float* p = ws + 4096;                 // data starts at +16 KB (zeroed region)
  A_.gates0 = p; p += (size_t)kB * kGates;
  A_.gates1 = p; p += (size_t)kB * kGates;
  A_.praw0  = p; p += (size_t)kB * kPRow;
  A_.praw1  = p; p += (size_t)kB * kPRow;
  A_.cat    = p; p += (size_t)kB * kCatW;
  A_.kwb    = p; p += (size_t)3 * kB * kM;
  A_.krb    = p; p += (size_t)3 * kB * kM;
  A_.evb    = p; p += (size_t)3 * kB * kM;
  A_.avb    = p; p += (size_t)3 * kB * kM;
  A_.scal   = p; p += (size_t)6 * kB * 8;
  A_.sdot   = p; p += (size_t)kB * 8;
  A_.wp0    = p; p += (size_t)kWN;
  A_.wp1    = p; p += (size_t)kWN;
  A_.wp2    = p; p += (size_t)kWN;
  A_.wp3    = p; p += (size_t)kWN;
  A_.wp4    = p; p += (size_t)kWN;
  A_.wp5    = p; p += (size_t)kWN;
  A_.mA     = p; p += (size_t)kWN * 12;
  A_.mB     = p; p += (size_t)kWN * 12;

  hipMemsetAsync(d_ws, 0, 16384, stream);
  mega<<<dim3(GRID), dim3(TPB), 0, stream>>>(A_);

  (void)in_sizes; (void)n_in; (void)out_size; (void)ws_size;
}